// Round 1
// 687.077 us; speedup vs baseline: 1.0070x; 1.0070x over previous
//
#include <hip/hip_runtime.h>

#define NCOLS 4096
#define QMAXF 127.0f
#define EPSF 1e-5f

// Vector type that works with __builtin_nontemporal_{load,store}
typedef float f4 __attribute__((ext_vector_type(4)));

// Structure: one block per row (4096 cols), 256 threads, 16 elems/thread.
// Two passes, ONE fused block reduction:
//   P1: load x1,x2 (nt), v = x1+x2, write xsum (nt), accumulate
//       ssq, amax|v*g*m1|, amax|v*g*m2|   (inv_rms factored OUT of amax —
//       it is a positive row constant, so max commutes with the scaling)
//   reduce (ssq, a1, a2) in one shuffle+LDS round; t==0 derives inv_rms,
//   scales, and per-row reciprocals (2 scalar IEEE divs per row).
//   P2: y = v*invrms*g, write ynorm (nt); quantize with multiply-by-
//       reciprocal + rintf; write y1,y2 (nt).
// gamma/sm1/sm2 (48 KB total) are loaded with REGULAR loads so they stay
// L2-resident across all 8192 blocks; the six big streams are nontemporal.
__global__ __launch_bounds__(256) void fused_addrms_dualquant(
    const float* __restrict__ x1,
    const float* __restrict__ x2,
    const float* __restrict__ gamma,
    const float* __restrict__ sm1,
    const float* __restrict__ sm2,
    float* __restrict__ o_xsum,
    float* __restrict__ o_ynorm,
    float* __restrict__ o_y1,
    float* __restrict__ o_s1,
    float* __restrict__ o_y2,
    float* __restrict__ o_s2)
{
    const int row = blockIdx.x;
    const long long base = (long long)row * NCOLS;
    const int t = threadIdx.x;

    f4 v[4];
    float ssq = 0.f, a1 = 0.f, a2 = 0.f;

    // ---- pass 1: residual add + xsum store + fused stats ----
#pragma unroll
    for (int c = 0; c < 4; ++c) {
        const int idx = c * 1024 + t * 4;
        f4 xa = __builtin_nontemporal_load((const f4*)(x1 + base + idx));
        f4 xb = __builtin_nontemporal_load((const f4*)(x2 + base + idx));
        f4 s = xa + xb;
        v[c] = s;
        ssq += s.x * s.x + s.y * s.y + s.z * s.z + s.w * s.w;
        __builtin_nontemporal_store(s, (f4*)(o_xsum + base + idx));

        f4 g  = *(const f4*)(gamma + idx);
        f4 m1 = *(const f4*)(sm1 + idx);
        f4 m2 = *(const f4*)(sm2 + idx);
        f4 gg = s * g;
        f4 p1 = gg * m1;
        f4 p2 = gg * m2;
        a1 = fmaxf(a1, fmaxf(fmaxf(fabsf(p1.x), fabsf(p1.y)),
                             fmaxf(fabsf(p1.z), fabsf(p1.w))));
        a2 = fmaxf(a2, fmaxf(fmaxf(fabsf(p2.x), fabsf(p2.y)),
                             fmaxf(fabsf(p2.z), fabsf(p2.w))));
    }

    // ---- single fused block reduction: (ssq, a1, a2) ----
#pragma unroll
    for (int off = 32; off > 0; off >>= 1) {
        ssq += __shfl_down(ssq, off);
        a1 = fmaxf(a1, __shfl_down(a1, off));
        a2 = fmaxf(a2, __shfl_down(a2, off));
    }

    __shared__ float red[12];   // [0..3]=ssq, [4..7]=a1, [8..11]=a2 per wave
    __shared__ float bc[3];     // invrms, 1/sc1, 1/sc2
    if ((t & 63) == 0) {
        const int w = t >> 6;
        red[w]     = ssq;
        red[4 + w] = a1;
        red[8 + w] = a2;
    }
    __syncthreads();
    if (t == 0) {
        float tot = red[0] + red[1] + red[2] + red[3];
        float invrms = rsqrtf(tot * (1.0f / (float)NCOLS) + EPSF);
        float am1 = fmaxf(fmaxf(red[4], red[5]), fmaxf(red[6], red[7])) * invrms;
        float am2 = fmaxf(fmaxf(red[8], red[9]), fmaxf(red[10], red[11])) * invrms;
        float sc1 = am1 / QMAXF;
        float sc2 = am2 / QMAXF;
        o_s1[row] = sc1;
        o_s2[row] = sc2;
        bc[0] = invrms;
        bc[1] = 1.0f / sc1;   // per-row reciprocal: 2 IEEE divs per ROW,
        bc[2] = 1.0f / sc2;   // replaces 32 IEEE divs per THREAD
    }
    __syncthreads();
    const float invrms = bc[0];
    const float r1 = bc[1];
    const float r2 = bc[2];

    // ---- pass 2: ynorm + dual quantize (gamma/sm reloads hit L2) ----
#pragma unroll
    for (int c = 0; c < 4; ++c) {
        const int idx = c * 1024 + t * 4;
        f4 g  = *(const f4*)(gamma + idx);
        f4 m1 = *(const f4*)(sm1 + idx);
        f4 m2 = *(const f4*)(sm2 + idx);

        f4 y = v[c] * invrms * g;           // (v*invrms)*g — ref association
        __builtin_nontemporal_store(y, (f4*)(o_ynorm + base + idx));

        f4 ys1 = y * m1;
        f4 ys2 = y * m2;
        f4 q1, q2;
        q1.x = fminf(fmaxf(rintf(ys1.x * r1), -128.f), 127.f);
        q1.y = fminf(fmaxf(rintf(ys1.y * r1), -128.f), 127.f);
        q1.z = fminf(fmaxf(rintf(ys1.z * r1), -128.f), 127.f);
        q1.w = fminf(fmaxf(rintf(ys1.w * r1), -128.f), 127.f);
        q2.x = fminf(fmaxf(rintf(ys2.x * r2), -128.f), 127.f);
        q2.y = fminf(fmaxf(rintf(ys2.y * r2), -128.f), 127.f);
        q2.z = fminf(fmaxf(rintf(ys2.z * r2), -128.f), 127.f);
        q2.w = fminf(fmaxf(rintf(ys2.w * r2), -128.f), 127.f);
        __builtin_nontemporal_store(q1, (f4*)(o_y1 + base + idx));
        __builtin_nontemporal_store(q2, (f4*)(o_y2 + base + idx));
    }
}

extern "C" void kernel_launch(void* const* d_in, const int* in_sizes, int n_in,
                              void* d_out, int out_size, void* d_ws, size_t ws_size,
                              hipStream_t stream) {
    const float* x1    = (const float*)d_in[0];
    const float* x2    = (const float*)d_in[1];
    const float* gamma = (const float*)d_in[2];
    const float* sm1   = (const float*)d_in[3];
    const float* sm2   = (const float*)d_in[4];

    const long long n_elem = in_sizes[0];        // B*S*N
    const int ncols = in_sizes[2];               // N = 4096
    const long long rows = n_elem / ncols;       // B*S = 8192

    float* out = (float*)d_out;
    float* o_xsum  = out;
    float* o_ynorm = out + n_elem;
    float* o_y1    = out + 2 * n_elem;
    float* o_s1    = out + 3 * n_elem;
    float* o_y2    = o_s1 + rows;
    float* o_s2    = o_y2 + n_elem;

    fused_addrms_dualquant<<<dim3((unsigned)rows), dim3(256), 0, stream>>>(
        x1, x2, gamma, sm1, sm2, o_xsum, o_ynorm, o_y1, o_s1, o_y2, o_s2);
}